// Round 1
// baseline (415.765 us; speedup 1.0000x reference)
//
#include <hip/hip_runtime.h>
#include <hip/hip_fp16.h>

// GCN link-prediction forward. CSR aggregation, row-major fp16 gather tables
// for the aggregates; XCD-sliced L2-resident z for decode (zs[4][N][32], slice
// = blockIdx&3) with quad-per-edge gather (1 line-request per 64B row) and
// dot2 inner product; fp16 MFMA GEMMs; parallel 3-pass prefix scan for CSR.
// Inputs: x[N,256] f32, train_edges[2,E] i32, pos[2,E] i32, neg[2,E] i32,
//         W1[256,256], b1[256], W2[256,128], b2[128]  (all f32)
// Output: logits[2E] f32.

#define NFEAT 256
#define HID   256
#define OUTF  128

typedef _Float16 f16x8 __attribute__((ext_vector_type(8)));
typedef _Float16 f16x2 __attribute__((ext_vector_type(2)));
typedef float    f32x4 __attribute__((ext_vector_type(4)));

// ---------------- degree ----------------
__global__ void k_init_deg(float* __restrict__ deg, int n) {
    int i = blockIdx.x * blockDim.x + threadIdx.x;
    if (i < n) deg[i] = 1.0f;   // self-loop
}

__global__ void k_count_deg(const int* __restrict__ ei, float* __restrict__ deg, int E) {
    int e = blockIdx.x * blockDim.x + threadIdx.x;
    if (e < E) atomicAdd(&deg[ei[E + e]], 1.0f);   // dst row
}

// ---------------- parallel scan, pass 1: per-block exclusive scan ----------------
__global__ __launch_bounds__(1024) void k_scan1(
        const float* __restrict__ deg, int* __restrict__ excl,
        int* __restrict__ bsum, int n) {
    __shared__ int swsum[16];
    const int t = threadIdx.x, wave = t >> 6, lane = t & 63;
    const int i = blockIdx.x * 1024 + t;
    int v = (i < n) ? (int)deg[i] - 1 : 0;
    int sc = v;
#pragma unroll
    for (int off = 1; off < 64; off <<= 1) {
        int y = __shfl_up(sc, off);
        if (lane >= off) sc += y;
    }
    if (lane == 63) swsum[wave] = sc;
    __syncthreads();
    if (t < 16) {
        int w = swsum[t];
        int scw = w;
#pragma unroll
        for (int off = 1; off < 16; off <<= 1) {
            int y = __shfl_up(scw, off);
            if (t >= off) scw += y;
        }
        swsum[t] = scw - w;
        if (t == 15) bsum[blockIdx.x] = scw;
    }
    __syncthreads();
    if (i < n) excl[i] = swsum[wave] + (sc - v);
}

// ---------------- pass 2: scan the (<=64) block sums in one wave ----------------
__global__ void k_scan2(int* __restrict__ bsum, int nb) {
    int t = threadIdx.x;          // 64 threads
    int v = (t < nb) ? bsum[t] : 0;
    int sc = v;
#pragma unroll
    for (int off = 1; off < 64; off <<= 1) {
        int y = __shfl_up(sc, off);
        if (t >= off) sc += y;
    }
    if (t < nb) bsum[t] = sc - v;   // exclusive
    if (t == 63) bsum[nb] = sc;     // grand total
}

// ---------------- pass 3: rowptr/cursor/dinv ----------------
__global__ void k_scan3(float* __restrict__ deg_dinv, const int* __restrict__ excl,
                        const int* __restrict__ bsum, int* __restrict__ rowptr,
                        int* __restrict__ cursor, int n, int nb) {
    int i = blockIdx.x * blockDim.x + threadIdx.x;
    if (i < n) {
        int rp = excl[i] + bsum[i >> 10];
        rowptr[i] = rp;
        cursor[i] = rp;
        deg_dinv[i] = rsqrtf(deg_dinv[i]);
    } else if (i == n) {
        rowptr[n] = bsum[nb];
    }
}

// ---------------- fill CSR adjacency (src ids grouped by dst) ----------------
__global__ void k_fill(const int* __restrict__ ei, int* __restrict__ cursor,
                       int* __restrict__ eidx, int E) {
    int e = blockIdx.x * blockDim.x + threadIdx.x;
    if (e < E) {
        int s = ei[e];
        int d = ei[E + e];
        int p = atomicAdd(&cursor[d], 1);
        eidx[p] = s;
    }
}

// ---------------- W transpose+convert: Wt[m][k] = (half)W[k][m] ----------------
__global__ __launch_bounds__(256) void k_wt(const float* __restrict__ W,
                                            __half* __restrict__ Wt, int K, int M) {
    __shared__ float tile[32][33];
    int k0 = blockIdx.x * 32, m0 = blockIdx.y * 32;
    int tx = threadIdx.x & 31, ty = threadIdx.x >> 5;  // ty 0..7
#pragma unroll
    for (int r = 0; r < 4; ++r)
        tile[ty + r * 8][tx] = W[(size_t)(k0 + ty + r * 8) * M + m0 + tx];
    __syncthreads();
#pragma unroll
    for (int r = 0; r < 4; ++r)
        Wt[(size_t)(m0 + ty + r * 8) * K + k0 + tx] = __float2half(tile[tx][ty + r * 8]);
}

// ---------------- MFMA GEMM: out = (half)(dinv[r] * A @ Wt^T) ----------------
// Block: 256 threads = 4 waves (2x2). Block tile (2*MT*16) x 128, wave (MT*16) x 64.
// A: [n][K] (f32 if AF32 else f16). Wt: [M][K] f16. K % 32 == 0.
// SWL=8 for M=256 / SWL=7 for M=128 give plain row-major output.
template <int MT, bool AF32, int SWL>
__global__ __launch_bounds__(256) void k_gemm_mfma(
        const void* __restrict__ Aptr, const __half* __restrict__ Wt,
        const float* __restrict__ dinv, __half* __restrict__ outp,
        int n, int K, int M) {
    constexpr int BM = 2 * MT * 16;
    __shared__ __half As[BM][40];      // [row][k], +8 pad: 2-way banks (free)
    __shared__ __half Bs[128][40];     // [col][k]
    __shared__ __half Cs[4][16][72];   // per-wave C repack (16B-aligned rows)

    const int t    = threadIdx.x;
    const int wave = t >> 6;
    const int lane = t & 63;
    const int row0 = blockIdx.x * BM;
    const int col0 = blockIdx.y * 128;
    const int wm = wave >> 1, wn = wave & 1;
    const int lr = lane & 15;          // fragment m/n index
    const int kq = lane >> 4;          // k-quad: k = kq*8 + j

    f32x4 acc[MT][4];
#pragma unroll
    for (int i = 0; i < MT; ++i)
#pragma unroll
        for (int j = 0; j < 4; ++j) acc[i][j] = (f32x4){0.f, 0.f, 0.f, 0.f};

    for (int k0 = 0; k0 < K; k0 += 32) {
        // ---- stage A tile: BM rows x 32 k ----
        if (AF32) {
            const float* A = (const float*)Aptr;
#pragma unroll
            for (int it = 0; it < BM * 8 / 256; ++it) {
                int q = t + it * 256;
                int r = q >> 3, c4 = q & 7;       // c4: which 4-float chunk
                int gr = min(row0 + r, n - 1);
                float4 v = *(const float4*)&A[(size_t)gr * K + k0 + c4 * 4];
                __half2* dst = (__half2*)&As[r][c4 * 4];
                dst[0] = __floats2half2_rn(v.x, v.y);
                dst[1] = __floats2half2_rn(v.z, v.w);
            }
        } else {
            const __half* A = (const __half*)Aptr;
#pragma unroll
            for (int it = 0; it < BM * 4 / 256; ++it) {
                int q = t + it * 256;
                int r = q >> 2, c8 = q & 3;       // c8: which 8-half chunk
                int gr = min(row0 + r, n - 1);
                *(float4*)&As[r][c8 * 8] = *(const float4*)&A[(size_t)gr * K + k0 + c8 * 8];
            }
        }
        // ---- stage B tile: 128 cols x 32 k from Wt ----
#pragma unroll
        for (int it = 0; it < 2; ++it) {
            int q = t + it * 256;
            int r = q >> 2, c8 = q & 3;
            *(float4*)&Bs[r][c8 * 8] = *(const float4*)&Wt[(size_t)(col0 + r) * K + k0 + c8 * 8];
        }
        __syncthreads();

        f16x8 b[4];
#pragma unroll
        for (int j = 0; j < 4; ++j)
            b[j] = *(const f16x8*)&Bs[wn * 64 + j * 16 + lr][kq * 8];
#pragma unroll
        for (int i = 0; i < MT; ++i) {
            f16x8 a = *(const f16x8*)&As[wm * MT * 16 + i * 16 + lr][kq * 8];
#pragma unroll
            for (int j = 0; j < 4; ++j)
                acc[i][j] = __builtin_amdgcn_mfma_f32_16x16x32_f16(a, b[j], acc[i][j], 0, 0, 0);
        }
        __syncthreads();
    }

    // ---- epilogue: scale by dinv, f16 convert, repack via LDS, 16-B stores ----
    constexpr int SW = 1 << SWL;
#pragma unroll
    for (int i = 0; i < MT; ++i) {
        int gr0 = row0 + wm * MT * 16 + i * 16;
        float dv[4];
#pragma unroll
        for (int r = 0; r < 4; ++r)
            dv[r] = dinv[min(gr0 + kq * 4 + r, n - 1)];
        __syncthreads();   // protect Cs reuse across i iterations
#pragma unroll
        for (int j = 0; j < 4; ++j)
#pragma unroll
            for (int r = 0; r < 4; ++r)
                Cs[wave][kq * 4 + r][j * 16 + lr] = __float2half(acc[i][j][r] * dv[r]);
        __syncthreads();
        int r1 = lane >> 3, c1 = (lane & 7) * 8;
#pragma unroll
        for (int h = 0; h < 2; ++h) {
            int grow = gr0 + r1 + h * 8;
            if (grow < n) {
                int col = col0 + wn * 64 + c1;    // multiple of 8
                size_t oidx = ((size_t)(col >> SWL) * n + grow) * SW + (col & (SW - 1));
                *(float4*)&outp[oidx] = *(const float4*)&Cs[wave][r1 + h * 8][c1];
            }
        }
    }
}

// ---------------- layer-1 aggregate: wave per node, 2 edges per load ----------
// g1 row-major [n][256] f16 (512B rows). lane = half(row sel) x 32 chunks x 16B.
__global__ __launch_bounds__(256) void k_agg1(
        const int* __restrict__ rowptr, const int* __restrict__ eidx,
        const __half* __restrict__ g, const float* __restrict__ dinv,
        const float* __restrict__ bias, __half* __restrict__ out, int n) {
    const int node = (int)(((size_t)blockIdx.x * blockDim.x + threadIdx.x) >> 6);
    const int lane = threadIdx.x & 63;
    const int half = lane >> 5;        // which of 2 rows this lane reads
    const int fl   = lane & 31;        // 16B chunk within row (8 halves)
    if (node >= n) return;
    const int j0  = rowptr[node];
    const int end = rowptr[node + 1];
    const int last = end - 1;          // only used when end > j0

    union U { float4 f; __half2 h[4]; };
    float acc[8] = {0.f, 0.f, 0.f, 0.f, 0.f, 0.f, 0.f, 0.f};
    {   // self row: half 0 only (avoid double count)
        if (half == 0) {
            U u; u.f = *(const float4*)&g[(size_t)node * HID + fl * 8];
#pragma unroll
            for (int k = 0; k < 4; ++k) {
                float2 v = __half22float2(u.h[k]);
                acc[k * 2] += v.x; acc[k * 2 + 1] += v.y;
            }
        }
    }
    if (j0 < end) {
        int s0 = eidx[min(j0 + half, last)];
        int s1 = eidx[min(j0 + 2 + half, last)];
        for (int j = j0; j < end; j += 4) {
            int p0 = eidx[min(j + 4 + half, last)];   // prefetch next iter's indices
            int p1 = eidx[min(j + 6 + half, last)];
            U u0, u1;
            u0.f = *(const float4*)&g[(size_t)s0 * HID + fl * 8];
            u1.f = *(const float4*)&g[(size_t)s1 * HID + fl * 8];
            if (j + half < end) {
#pragma unroll
                for (int k = 0; k < 4; ++k) {
                    float2 v = __half22float2(u0.h[k]);
                    acc[k * 2] += v.x; acc[k * 2 + 1] += v.y;
                }
            }
            if (j + 2 + half < end) {
#pragma unroll
                for (int k = 0; k < 4; ++k) {
                    float2 v = __half22float2(u1.h[k]);
                    acc[k * 2] += v.x; acc[k * 2 + 1] += v.y;
                }
            }
            s0 = p0; s1 = p1;
        }
    }
    // reduce across the two halves
#pragma unroll
    for (int k = 0; k < 8; ++k) acc[k] += __shfl_xor(acc[k], 32);
    if (half == 0) {
        const float sc = dinv[node];
        const int f0 = fl * 8;
        U r;
#pragma unroll
        for (int k = 0; k < 4; ++k) {
            float2 bb = *(const float2*)&bias[f0 + k * 2];
            r.h[k] = __floats2half2_rn(fmaxf(sc * acc[k * 2]     + bb.x, 0.f),
                                       fmaxf(sc * acc[k * 2 + 1] + bb.y, 0.f));
        }
        *(float4*)&out[(size_t)node * HID + f0] = r.f;
    }
}

// ---------------- layer-2 aggregate: wave per node, 4 edges per load ----------
// g2 row-major [n][128] f16 (256B rows) -> zs [4][n][32] f16 (sliced for decode).
__global__ __launch_bounds__(256) void k_agg2(
        const int* __restrict__ rowptr, const int* __restrict__ eidx,
        const __half* __restrict__ g, const float* __restrict__ dinv,
        const float* __restrict__ bias, __half* __restrict__ zs, int n) {
    const int node = (int)(((size_t)blockIdx.x * blockDim.x + threadIdx.x) >> 6);
    const int lane = threadIdx.x & 63;
    const int q    = lane >> 4;        // which of 4 rows this lane reads
    const int fl   = lane & 15;        // 16B chunk within row
    if (node >= n) return;
    const int j0  = rowptr[node];
    const int end = rowptr[node + 1];
    const int last = end - 1;

    union U { float4 f; __half2 h[4]; };
    float acc[8] = {0.f, 0.f, 0.f, 0.f, 0.f, 0.f, 0.f, 0.f};
    if (q == 0) {   // self row
        U u; u.f = *(const float4*)&g[(size_t)node * OUTF + fl * 8];
#pragma unroll
        for (int k = 0; k < 4; ++k) {
            float2 v = __half22float2(u.h[k]);
            acc[k * 2] += v.x; acc[k * 2 + 1] += v.y;
        }
    }
    if (j0 < end) {
        int s0 = eidx[min(j0 + q, last)];
        for (int j = j0; j < end; j += 4) {
            int p0 = eidx[min(j + 4 + q, last)];
            U u0; u0.f = *(const float4*)&g[(size_t)s0 * OUTF + fl * 8];
            if (j + q < end) {
#pragma unroll
                for (int k = 0; k < 4; ++k) {
                    float2 v = __half22float2(u0.h[k]);
                    acc[k * 2] += v.x; acc[k * 2 + 1] += v.y;
                }
            }
            s0 = p0;
        }
    }
#pragma unroll
    for (int k = 0; k < 8; ++k) {
        acc[k] += __shfl_xor(acc[k], 16);
        acc[k] += __shfl_xor(acc[k], 32);
    }
    if (q == 0) {
        const float sc = dinv[node];
        const int f0 = fl * 8;              // 0,8,...,120
        U r;
#pragma unroll
        for (int k = 0; k < 4; ++k) {
            float2 bb = *(const float2*)&bias[f0 + k * 2];
            r.h[k] = __floats2half2_rn(sc * acc[k * 2]     + bb.x,
                                       sc * acc[k * 2 + 1] + bb.y);
        }
        // slice-major store: slice = f0>>5, 16B chunk stays within slice
        *(float4*)&zs[((size_t)(f0 >> 5) * n + node) * 32 + (f0 & 31)] = r.f;
    }
}

// ---------------- decode (sliced): psum[slice][e], 16 edges/wave ----------------
// zs [4][n][32] f16; slice = bx & 3 (XCD-pinned, 3.2MB L2-resident).
// Quad-per-edge: lane = eo*4 + c; the 4 lanes of a quad load one FULL 64B row
// of each endpoint in a single instruction (1 line-request/row after quad
// coalescing, vs 2 in the old 2-lane layout) -> half the TA work per edge.
__global__ __launch_bounds__(256) void k_decode(
        const int* __restrict__ pos, const int* __restrict__ neg,
        const __half* __restrict__ zs, float* __restrict__ psum, int E, int n) {
    const int slice = blockIdx.x & 3;
    const int wv    = threadIdx.x >> 6;
    const int lane  = threadIdx.x & 63;
    const int eo    = lane >> 2;       // edge within wave (0..15)
    const int c     = lane & 3;        // 16B chunk within the 64B rows
    int e = ((blockIdx.x >> 2) * 4 + wv) * 16 + eo;
    if (e >= 2 * E) return;
    int a, b;
    if (e < E) { a = pos[e];     b = pos[E + e]; }
    else       { a = neg[e - E]; b = neg[e];     }   // neg row1 at E + (e-E) = e
    const __half* ra = zs + ((size_t)slice * n + a) * 32 + c * 8;
    const __half* rb = zs + ((size_t)slice * n + b) * 32 + c * 8;
    union U { float4 f; f16x2 d[4]; };
    U av, bv;
    av.f = *(const float4*)ra;
    bv.f = *(const float4*)rb;
    float p = 0.f;
#if __has_builtin(__builtin_amdgcn_fdot2)
#pragma unroll
    for (int k = 0; k < 4; ++k) p = __builtin_amdgcn_fdot2(av.d[k], bv.d[k], p, false);
#else
#pragma unroll
    for (int k = 0; k < 4; ++k) {
        p += (float)av.d[k][0] * (float)bv.d[k][0] + (float)av.d[k][1] * (float)bv.d[k][1];
    }
#endif
    p += __shfl_xor(p, 1);
    p += __shfl_xor(p, 2);
    if (c == 0)
        __builtin_nontemporal_store(p, &psum[(size_t)slice * 2 * E + e]);
}

// ---------------- final sum over 4 slices ----------------
__global__ void k_dsum(const float* __restrict__ psum, float* __restrict__ out, int n2e) {
    int e = blockIdx.x * blockDim.x + threadIdx.x;
    if (e < n2e) {
        float p0 = __builtin_nontemporal_load(&psum[e]);
        float p1 = __builtin_nontemporal_load(&psum[(size_t)n2e + e]);
        float p2 = __builtin_nontemporal_load(&psum[2 * (size_t)n2e + e]);
        float p3 = __builtin_nontemporal_load(&psum[3 * (size_t)n2e + e]);
        out[e] = (p0 + p1) + (p2 + p3);
    }
}

extern "C" void kernel_launch(void* const* d_in, const int* in_sizes, int n_in,
                              void* d_out, int out_size, void* d_ws, size_t ws_size,
                              hipStream_t stream) {
    const float* x   = (const float*)d_in[0];
    const int*   tei = (const int*)d_in[1];
    const int*   pos = (const int*)d_in[2];
    const int*   neg = (const int*)d_in[3];
    const float* W1  = (const float*)d_in[4];
    const float* b1  = (const float*)d_in[5];
    const float* W2  = (const float*)d_in[6];
    const float* b2  = (const float*)d_in[7];
    float* out = (float*)d_out;

    const int N = in_sizes[0] / NFEAT;    // 50000
    const int E = in_sizes[1] / 2;        // 800000
    const int NB = (N + 1023) / 1024;     // scan blocks (49)

    char* ws = (char*)d_ws;
    size_t off = 0;
    __half* g1h = (__half*)(ws + off);                 // [N][256] f16 (25.6MB)
    __half* g2h = (__half*)(ws + off);                 // [N][128] f16 (g1 dead)
    __half* zs  = (__half*)(ws + off + (size_t)N * OUTF * 2);   // [4][N][32] f16
    off += (size_t)N * HID * 2;
    __half* h1h  = (__half*)(ws + off);                // [N][256] f16 (25.6MB)
    float*  psum = (float*)(ws + off);                 // [4][2E] f32 (h1 dead after gemm2)
    off += (size_t)N * HID * 2;
    float*  dinv = (float*)(ws + off);  off += (size_t)N * 4;
    int* rowptr = (int*)(ws + off);     off += (size_t)(N + 1) * 4;
    int* cursor = (int*)(ws + off);     off += (size_t)N * 4;
    int* eidx   = (int*)(ws + off);     off += (size_t)E * 4;
    __half* W1t = (__half*)(ws + off);  off += (size_t)NFEAT * HID * 2;
    __half* W2t = (__half*)(ws + off);  off += (size_t)HID * OUTF * 2;
    int* excl   = (int*)(ws + off);     off += (size_t)N * 4;
    int* bsum   = (int*)(ws + off);     off += (size_t)(NB + 1) * 4;

    // 0) weight transpose+convert
    { dim3 g(NFEAT / 32, HID / 32);  k_wt<<<g, 256, 0, stream>>>(W1, W1t, NFEAT, HID); }
    { dim3 g(HID / 32, OUTF / 32);   k_wt<<<g, 256, 0, stream>>>(W2, W2t, HID, OUTF); }

    // 1) degree -> parallel scan -> CSR fill (shared by both layers)
    k_init_deg<<<(N + 255) / 256, 256, 0, stream>>>(dinv, N);
    k_count_deg<<<(E + 255) / 256, 256, 0, stream>>>(tei, dinv, E);
    k_scan1<<<NB, 1024, 0, stream>>>(dinv, excl, bsum, N);
    k_scan2<<<1, 64, 0, stream>>>(bsum, NB);
    k_scan3<<<(N + 256) / 256, 256, 0, stream>>>(dinv, excl, bsum, rowptr, cursor, N, NB);
    k_fill<<<(E + 255) / 256, 256, 0, stream>>>(tei, cursor, eidx, E);

    // 2) layer 1: g1 = (f16) dinv*(x@W1); h1 = (f16) relu(dinv*(agg+self)+b1)
    {
        dim3 grid((N + 127) / 128, HID / 128);
        k_gemm_mfma<4, true, 8><<<grid, 256, 0, stream>>>(x, W1t, dinv, g1h, N, NFEAT, HID);
        int nblk = (int)(((size_t)N * 64 + 255) / 256);
        k_agg1<<<nblk, 256, 0, stream>>>(rowptr, eidx, g1h, dinv, b1, h1h, N);
    }

    // 3) layer 2: g2 = (f16) dinv*(h1@W2); zs = (f16, [4][N][32]) dinv*(agg+self)+b2
    {
        dim3 grid((N + 63) / 64, OUTF / 128);
        k_gemm_mfma<2, false, 7><<<grid, 256, 0, stream>>>(h1h, W2t, dinv, g2h, N, HID, OUTF);
        int nblk = (int)(((size_t)N * 64 + 255) / 256);
        k_agg2<<<nblk, 256, 0, stream>>>(rowptr, eidx, g2h, dinv, b2, zs, N);
    }

    // 4) decode: sliced partial dots (quad-per-edge) + final sum
    {
        int nblk = 4 * ((2 * E + 63) / 64);   // 4 waves x 16 edges per block
        k_decode<<<nblk, 256, 0, stream>>>(pos, neg, zs, psum, E, N);
        k_dsum<<<(2 * E + 255) / 256, 256, 0, stream>>>(psum, out, 2 * E);
    }
}

// Round 3
// 413.177 us; speedup vs baseline: 1.0063x; 1.0063x over previous
//
#include <hip/hip_runtime.h>
#include <hip/hip_fp16.h>

// GCN link-prediction forward. CSR aggregation, row-major fp16 gather tables
// for the aggregates; XCD-sliced L2-resident z for decode (zs[4][N][32], slice
// = blockIdx&3) with dot2-based gather; decode uses persistent waves with a
// software-pipelined 8x32-edge loop (prefetch next indices under gathers);
// fp16 MFMA GEMMs; parallel 3-pass prefix scan for CSR rowptr.
// Inputs: x[N,256] f32, train_edges[2,E] i32, pos[2,E] i32, neg[2,E] i32,
//         W1[256,256], b1[256], W2[256,128], b2[128]  (all f32)
// Output: logits[2E] f32.

#define NFEAT 256
#define HID   256
#define OUTF  128
#define DEC_ITER 8

typedef _Float16 f16x8 __attribute__((ext_vector_type(8)));
typedef _Float16 f16x2 __attribute__((ext_vector_type(2)));
typedef float    f32x4 __attribute__((ext_vector_type(4)));

// ---------------- degree ----------------
__global__ void k_init_deg(float* __restrict__ deg, int n) {
    int i = blockIdx.x * blockDim.x + threadIdx.x;
    if (i < n) deg[i] = 1.0f;   // self-loop
}

__global__ void k_count_deg(const int* __restrict__ ei, float* __restrict__ deg, int E) {
    int e = blockIdx.x * blockDim.x + threadIdx.x;
    if (e < E) atomicAdd(&deg[ei[E + e]], 1.0f);   // dst row
}

// ---------------- parallel scan, pass 1: per-block exclusive scan ----------------
__global__ __launch_bounds__(1024) void k_scan1(
        const float* __restrict__ deg, int* __restrict__ excl,
        int* __restrict__ bsum, int n) {
    __shared__ int swsum[16];
    const int t = threadIdx.x, wave = t >> 6, lane = t & 63;
    const int i = blockIdx.x * 1024 + t;
    int v = (i < n) ? (int)deg[i] - 1 : 0;
    int sc = v;
#pragma unroll
    for (int off = 1; off < 64; off <<= 1) {
        int y = __shfl_up(sc, off);
        if (lane >= off) sc += y;
    }
    if (lane == 63) swsum[wave] = sc;
    __syncthreads();
    if (t < 16) {
        int w = swsum[t];
        int scw = w;
#pragma unroll
        for (int off = 1; off < 16; off <<= 1) {
            int y = __shfl_up(scw, off);
            if (t >= off) scw += y;
        }
        swsum[t] = scw - w;
        if (t == 15) bsum[blockIdx.x] = scw;
    }
    __syncthreads();
    if (i < n) excl[i] = swsum[wave] + (sc - v);
}

// ---------------- pass 2: scan the (<=64) block sums in one wave ----------------
__global__ void k_scan2(int* __restrict__ bsum, int nb) {
    int t = threadIdx.x;          // 64 threads
    int v = (t < nb) ? bsum[t] : 0;
    int sc = v;
#pragma unroll
    for (int off = 1; off < 64; off <<= 1) {
        int y = __shfl_up(sc, off);
        if (t >= off) sc += y;
    }
    if (t < nb) bsum[t] = sc - v;   // exclusive
    if (t == 63) bsum[nb] = sc;     // grand total
}

// ---------------- pass 3: rowptr/cursor/dinv ----------------
__global__ void k_scan3(float* __restrict__ deg_dinv, const int* __restrict__ excl,
                        const int* __restrict__ bsum, int* __restrict__ rowptr,
                        int* __restrict__ cursor, int n, int nb) {
    int i = blockIdx.x * blockDim.x + threadIdx.x;
    if (i < n) {
        int rp = excl[i] + bsum[i >> 10];
        rowptr[i] = rp;
        cursor[i] = rp;
        deg_dinv[i] = rsqrtf(deg_dinv[i]);
    } else if (i == n) {
        rowptr[n] = bsum[nb];
    }
}

// ---------------- fill CSR adjacency (src ids grouped by dst) ----------------
__global__ void k_fill(const int* __restrict__ ei, int* __restrict__ cursor,
                       int* __restrict__ eidx, int E) {
    int e = blockIdx.x * blockDim.x + threadIdx.x;
    if (e < E) {
        int s = ei[e];
        int d = ei[E + e];
        int p = atomicAdd(&cursor[d], 1);
        eidx[p] = s;
    }
}

// ---------------- W transpose+convert: Wt[m][k] = (half)W[k][m] ----------------
__global__ __launch_bounds__(256) void k_wt(const float* __restrict__ W,
                                            __half* __restrict__ Wt, int K, int M) {
    __shared__ float tile[32][33];
    int k0 = blockIdx.x * 32, m0 = blockIdx.y * 32;
    int tx = threadIdx.x & 31, ty = threadIdx.x >> 5;  // ty 0..7
#pragma unroll
    for (int r = 0; r < 4; ++r)
        tile[ty + r * 8][tx] = W[(size_t)(k0 + ty + r * 8) * M + m0 + tx];
    __syncthreads();
#pragma unroll
    for (int r = 0; r < 4; ++r)
        Wt[(size_t)(m0 + ty + r * 8) * K + k0 + tx] = __float2half(tile[tx][ty + r * 8]);
}

// ---------------- MFMA GEMM: out = (half)(dinv[r] * A @ Wt^T) ----------------
// Block: 256 threads = 4 waves (2x2). Block tile (2*MT*16) x 128, wave (MT*16) x 64.
// A: [n][K] (f32 if AF32 else f16). Wt: [M][K] f16. K % 32 == 0.
// SWL=8 for M=256 / SWL=7 for M=128 give plain row-major output.
template <int MT, bool AF32, int SWL>
__global__ __launch_bounds__(256) void k_gemm_mfma(
        const void* __restrict__ Aptr, const __half* __restrict__ Wt,
        const float* __restrict__ dinv, __half* __restrict__ outp,
        int n, int K, int M) {
    constexpr int BM = 2 * MT * 16;
    __shared__ __half As[BM][40];      // [row][k], +8 pad: 2-way banks (free)
    __shared__ __half Bs[128][40];     // [col][k]
    __shared__ __half Cs[4][16][72];   // per-wave C repack (16B-aligned rows)

    const int t    = threadIdx.x;
    const int wave = t >> 6;
    const int lane = t & 63;
    const int row0 = blockIdx.x * BM;
    const int col0 = blockIdx.y * 128;
    const int wm = wave >> 1, wn = wave & 1;
    const int lr = lane & 15;          // fragment m/n index
    const int kq = lane >> 4;          // k-quad: k = kq*8 + j

    f32x4 acc[MT][4];
#pragma unroll
    for (int i = 0; i < MT; ++i)
#pragma unroll
        for (int j = 0; j < 4; ++j) acc[i][j] = (f32x4){0.f, 0.f, 0.f, 0.f};

    for (int k0 = 0; k0 < K; k0 += 32) {
        // ---- stage A tile: BM rows x 32 k ----
        if (AF32) {
            const float* A = (const float*)Aptr;
#pragma unroll
            for (int it = 0; it < BM * 8 / 256; ++it) {
                int q = t + it * 256;
                int r = q >> 3, c4 = q & 7;       // c4: which 4-float chunk
                int gr = min(row0 + r, n - 1);
                float4 v = *(const float4*)&A[(size_t)gr * K + k0 + c4 * 4];
                __half2* dst = (__half2*)&As[r][c4 * 4];
                dst[0] = __floats2half2_rn(v.x, v.y);
                dst[1] = __floats2half2_rn(v.z, v.w);
            }
        } else {
            const __half* A = (const __half*)Aptr;
#pragma unroll
            for (int it = 0; it < BM * 4 / 256; ++it) {
                int q = t + it * 256;
                int r = q >> 2, c8 = q & 3;       // c8: which 8-half chunk
                int gr = min(row0 + r, n - 1);
                *(float4*)&As[r][c8 * 8] = *(const float4*)&A[(size_t)gr * K + k0 + c8 * 8];
            }
        }
        // ---- stage B tile: 128 cols x 32 k from Wt ----
#pragma unroll
        for (int it = 0; it < 2; ++it) {
            int q = t + it * 256;
            int r = q >> 2, c8 = q & 3;
            *(float4*)&Bs[r][c8 * 8] = *(const float4*)&Wt[(size_t)(col0 + r) * K + k0 + c8 * 8];
        }
        __syncthreads();

        f16x8 b[4];
#pragma unroll
        for (int j = 0; j < 4; ++j)
            b[j] = *(const f16x8*)&Bs[wn * 64 + j * 16 + lr][kq * 8];
#pragma unroll
        for (int i = 0; i < MT; ++i) {
            f16x8 a = *(const f16x8*)&As[wm * MT * 16 + i * 16 + lr][kq * 8];
#pragma unroll
            for (int j = 0; j < 4; ++j)
                acc[i][j] = __builtin_amdgcn_mfma_f32_16x16x32_f16(a, b[j], acc[i][j], 0, 0, 0);
        }
        __syncthreads();
    }

    // ---- epilogue: scale by dinv, f16 convert, repack via LDS, 16-B stores ----
    constexpr int SW = 1 << SWL;
#pragma unroll
    for (int i = 0; i < MT; ++i) {
        int gr0 = row0 + wm * MT * 16 + i * 16;
        float dv[4];
#pragma unroll
        for (int r = 0; r < 4; ++r)
            dv[r] = dinv[min(gr0 + kq * 4 + r, n - 1)];
        __syncthreads();   // protect Cs reuse across i iterations
#pragma unroll
        for (int j = 0; j < 4; ++j)
#pragma unroll
            for (int r = 0; r < 4; ++r)
                Cs[wave][kq * 4 + r][j * 16 + lr] = __float2half(acc[i][j][r] * dv[r]);
        __syncthreads();
        int r1 = lane >> 3, c1 = (lane & 7) * 8;
#pragma unroll
        for (int h = 0; h < 2; ++h) {
            int grow = gr0 + r1 + h * 8;
            if (grow < n) {
                int col = col0 + wn * 64 + c1;    // multiple of 8
                size_t oidx = ((size_t)(col >> SWL) * n + grow) * SW + (col & (SW - 1));
                *(float4*)&outp[oidx] = *(const float4*)&Cs[wave][r1 + h * 8][c1];
            }
        }
    }
}

// ---------------- layer-1 aggregate: wave per node, 2 edges per load ----------
// g1 row-major [n][256] f16 (512B rows). lane = half(row sel) x 32 chunks x 16B.
__global__ __launch_bounds__(256) void k_agg1(
        const int* __restrict__ rowptr, const int* __restrict__ eidx,
        const __half* __restrict__ g, const float* __restrict__ dinv,
        const float* __restrict__ bias, __half* __restrict__ out, int n) {
    const int node = (int)(((size_t)blockIdx.x * blockDim.x + threadIdx.x) >> 6);
    const int lane = threadIdx.x & 63;
    const int half = lane >> 5;        // which of 2 rows this lane reads
    const int fl   = lane & 31;        // 16B chunk within row (8 halves)
    if (node >= n) return;
    const int j0  = rowptr[node];
    const int end = rowptr[node + 1];
    const int last = end - 1;          // only used when end > j0

    union U { float4 f; __half2 h[4]; };
    float acc[8] = {0.f, 0.f, 0.f, 0.f, 0.f, 0.f, 0.f, 0.f};
    {   // self row: half 0 only (avoid double count)
        if (half == 0) {
            U u; u.f = *(const float4*)&g[(size_t)node * HID + fl * 8];
#pragma unroll
            for (int k = 0; k < 4; ++k) {
                float2 v = __half22float2(u.h[k]);
                acc[k * 2] += v.x; acc[k * 2 + 1] += v.y;
            }
        }
    }
    if (j0 < end) {
        int s0 = eidx[min(j0 + half, last)];
        int s1 = eidx[min(j0 + 2 + half, last)];
        for (int j = j0; j < end; j += 4) {
            int p0 = eidx[min(j + 4 + half, last)];   // prefetch next iter's indices
            int p1 = eidx[min(j + 6 + half, last)];
            U u0, u1;
            u0.f = *(const float4*)&g[(size_t)s0 * HID + fl * 8];
            u1.f = *(const float4*)&g[(size_t)s1 * HID + fl * 8];
            if (j + half < end) {
#pragma unroll
                for (int k = 0; k < 4; ++k) {
                    float2 v = __half22float2(u0.h[k]);
                    acc[k * 2] += v.x; acc[k * 2 + 1] += v.y;
                }
            }
            if (j + 2 + half < end) {
#pragma unroll
                for (int k = 0; k < 4; ++k) {
                    float2 v = __half22float2(u1.h[k]);
                    acc[k * 2] += v.x; acc[k * 2 + 1] += v.y;
                }
            }
            s0 = p0; s1 = p1;
        }
    }
    // reduce across the two halves
#pragma unroll
    for (int k = 0; k < 8; ++k) acc[k] += __shfl_xor(acc[k], 32);
    if (half == 0) {
        const float sc = dinv[node];
        const int f0 = fl * 8;
        U r;
#pragma unroll
        for (int k = 0; k < 4; ++k) {
            float2 bb = *(const float2*)&bias[f0 + k * 2];
            r.h[k] = __floats2half2_rn(fmaxf(sc * acc[k * 2]     + bb.x, 0.f),
                                       fmaxf(sc * acc[k * 2 + 1] + bb.y, 0.f));
        }
        *(float4*)&out[(size_t)node * HID + f0] = r.f;
    }
}

// ---------------- layer-2 aggregate: wave per node, 4 edges per load ----------
// g2 row-major [n][128] f16 (256B rows) -> zs [4][n][32] f16 (sliced for decode).
__global__ __launch_bounds__(256) void k_agg2(
        const int* __restrict__ rowptr, const int* __restrict__ eidx,
        const __half* __restrict__ g, const float* __restrict__ dinv,
        const float* __restrict__ bias, __half* __restrict__ zs, int n) {
    const int node = (int)(((size_t)blockIdx.x * blockDim.x + threadIdx.x) >> 6);
    const int lane = threadIdx.x & 63;
    const int q    = lane >> 4;        // which of 4 rows this lane reads
    const int fl   = lane & 15;        // 16B chunk within row
    if (node >= n) return;
    const int j0  = rowptr[node];
    const int end = rowptr[node + 1];
    const int last = end - 1;

    union U { float4 f; __half2 h[4]; };
    float acc[8] = {0.f, 0.f, 0.f, 0.f, 0.f, 0.f, 0.f, 0.f};
    if (q == 0) {   // self row
        U u; u.f = *(const float4*)&g[(size_t)node * OUTF + fl * 8];
#pragma unroll
        for (int k = 0; k < 4; ++k) {
            float2 v = __half22float2(u.h[k]);
            acc[k * 2] += v.x; acc[k * 2 + 1] += v.y;
        }
    }
    if (j0 < end) {
        int s0 = eidx[min(j0 + q, last)];
        for (int j = j0; j < end; j += 4) {
            int p0 = eidx[min(j + 4 + q, last)];
            U u0; u0.f = *(const float4*)&g[(size_t)s0 * OUTF + fl * 8];
            if (j + q < end) {
#pragma unroll
                for (int k = 0; k < 4; ++k) {
                    float2 v = __half22float2(u0.h[k]);
                    acc[k * 2] += v.x; acc[k * 2 + 1] += v.y;
                }
            }
            s0 = p0;
        }
    }
#pragma unroll
    for (int k = 0; k < 8; ++k) {
        acc[k] += __shfl_xor(acc[k], 16);
        acc[k] += __shfl_xor(acc[k], 32);
    }
    if (q == 0) {
        const float sc = dinv[node];
        const int f0 = fl * 8;              // 0,8,...,120
        U r;
#pragma unroll
        for (int k = 0; k < 4; ++k) {
            float2 bb = *(const float2*)&bias[f0 + k * 2];
            r.h[k] = __floats2half2_rn(sc * acc[k * 2]     + bb.x,
                                       sc * acc[k * 2 + 1] + bb.y);
        }
        // slice-major store: slice = f0>>5, 16B chunk stays within slice
        *(float4*)&zs[((size_t)(f0 >> 5) * n + node) * 32 + (f0 & 31)] = r.f;
    }
}

// ---------------- decode (sliced): psum[slice][e], pipelined 8x32 edges/wave --
// zs [4][n][32] f16; slice = bx & 3 (XCD-pinned, 3.2MB L2-resident).
// lane = (edge-in-group)*2 + h; lane loads 32B of BOTH endpoint rows, 16-feat
// dot. Each wave runs DEC_ITER groups, prefetching the next group's indices
// while the current group's gathers are in flight (hides L2 latency chain).
__global__ __launch_bounds__(256) void k_decode(
        const int* __restrict__ pos, const int* __restrict__ neg,
        const __half* __restrict__ zs, float* __restrict__ psum, int E, int n) {
    const int slice = blockIdx.x & 3;
    const int wv    = threadIdx.x >> 6;
    const int lane  = threadIdx.x & 63;
    const int eo    = lane >> 1;       // edge within group (0..31)
    const int h     = lane & 1;        // which 32B half of the 64B rows
    const int n2e   = 2 * E;
    const __half* zsl = zs + (size_t)slice * n * 32;
    float* psl = psum + (size_t)slice * n2e;

    int e = (((blockIdx.x >> 2) * 4 + wv) * DEC_ITER) * 32 + eo;
    int a, b;
    {   // initial index load
        int ec = min(e, n2e - 1);
        if (ec < E) { a = pos[ec];     b = pos[E + ec]; }
        else        { a = neg[ec - E]; b = neg[ec];     }
    }
#pragma unroll
    for (int it = 0; it < DEC_ITER; ++it) {
        const __half* ra = zsl + (size_t)a * 32 + h * 16;
        const __half* rb = zsl + (size_t)b * 32 + h * 16;
        union U { float4 f; f16x2 d[4]; };
        U a0, a1, b0, b1;
        a0.f = *(const float4*)&ra[0];
        a1.f = *(const float4*)&ra[8];
        b0.f = *(const float4*)&rb[0];
        b1.f = *(const float4*)&rb[8];
        // prefetch next group's indices while gathers are in flight
        const int en = e + 32;
        if (it + 1 < DEC_ITER) {
            int ec = min(en, n2e - 1);
            if (ec < E) { a = pos[ec];     b = pos[E + ec]; }
            else        { a = neg[ec - E]; b = neg[ec];     }
        }
        float p = 0.f;
#if __has_builtin(__builtin_amdgcn_fdot2)
#pragma unroll
        for (int k = 0; k < 4; ++k) p = __builtin_amdgcn_fdot2(a0.d[k], b0.d[k], p, false);
#pragma unroll
        for (int k = 0; k < 4; ++k) p = __builtin_amdgcn_fdot2(a1.d[k], b1.d[k], p, false);
#else
#pragma unroll
        for (int k = 0; k < 4; ++k) {
            p += (float)a0.d[k][0] * (float)b0.d[k][0] + (float)a0.d[k][1] * (float)b0.d[k][1];
            p += (float)a1.d[k][0] * (float)b1.d[k][0] + (float)a1.d[k][1] * (float)b1.d[k][1];
        }
#endif
        p += __shfl_xor(p, 1);
        if (h == 0 && e < n2e)
            __builtin_nontemporal_store(p, &psl[e]);
        e = en;
    }
}

// ---------------- final sum over 4 slices ----------------
__global__ void k_dsum(const float* __restrict__ psum, float* __restrict__ out, int n2e) {
    int e = blockIdx.x * blockDim.x + threadIdx.x;
    if (e < n2e) {
        float p0 = __builtin_nontemporal_load(&psum[e]);
        float p1 = __builtin_nontemporal_load(&psum[(size_t)n2e + e]);
        float p2 = __builtin_nontemporal_load(&psum[2 * (size_t)n2e + e]);
        float p3 = __builtin_nontemporal_load(&psum[3 * (size_t)n2e + e]);
        out[e] = (p0 + p1) + (p2 + p3);
    }
}

extern "C" void kernel_launch(void* const* d_in, const int* in_sizes, int n_in,
                              void* d_out, int out_size, void* d_ws, size_t ws_size,
                              hipStream_t stream) {
    const float* x   = (const float*)d_in[0];
    const int*   tei = (const int*)d_in[1];
    const int*   pos = (const int*)d_in[2];
    const int*   neg = (const int*)d_in[3];
    const float* W1  = (const float*)d_in[4];
    const float* b1  = (const float*)d_in[5];
    const float* W2  = (const float*)d_in[6];
    const float* b2  = (const float*)d_in[7];
    float* out = (float*)d_out;

    const int N = in_sizes[0] / NFEAT;    // 50000
    const int E = in_sizes[1] / 2;        // 800000
    const int NB = (N + 1023) / 1024;     // scan blocks (49)

    char* ws = (char*)d_ws;
    size_t off = 0;
    __half* g1h = (__half*)(ws + off);                 // [N][256] f16 (25.6MB)
    __half* g2h = (__half*)(ws + off);                 // [N][128] f16 (g1 dead)
    __half* zs  = (__half*)(ws + off + (size_t)N * OUTF * 2);   // [4][N][32] f16
    off += (size_t)N * HID * 2;
    __half* h1h  = (__half*)(ws + off);                // [N][256] f16 (25.6MB)
    float*  psum = (float*)(ws + off);                 // [4][2E] f32 (h1 dead after gemm2)
    off += (size_t)N * HID * 2;
    float*  dinv = (float*)(ws + off);  off += (size_t)N * 4;
    int* rowptr = (int*)(ws + off);     off += (size_t)(N + 1) * 4;
    int* cursor = (int*)(ws + off);     off += (size_t)N * 4;
    int* eidx   = (int*)(ws + off);     off += (size_t)E * 4;
    __half* W1t = (__half*)(ws + off);  off += (size_t)NFEAT * HID * 2;
    __half* W2t = (__half*)(ws + off);  off += (size_t)HID * OUTF * 2;
    int* excl   = (int*)(ws + off);     off += (size_t)N * 4;
    int* bsum   = (int*)(ws + off);     off += (size_t)(NB + 1) * 4;

    // 0) weight transpose+convert
    { dim3 g(NFEAT / 32, HID / 32);  k_wt<<<g, 256, 0, stream>>>(W1, W1t, NFEAT, HID); }
    { dim3 g(HID / 32, OUTF / 32);   k_wt<<<g, 256, 0, stream>>>(W2, W2t, HID, OUTF); }

    // 1) degree -> parallel scan -> CSR fill (shared by both layers)
    k_init_deg<<<(N + 255) / 256, 256, 0, stream>>>(dinv, N);
    k_count_deg<<<(E + 255) / 256, 256, 0, stream>>>(tei, dinv, E);
    k_scan1<<<NB, 1024, 0, stream>>>(dinv, excl, bsum, N);
    k_scan2<<<1, 64, 0, stream>>>(bsum, NB);
    k_scan3<<<(N + 256) / 256, 256, 0, stream>>>(dinv, excl, bsum, rowptr, cursor, N, NB);
    k_fill<<<(E + 255) / 256, 256, 0, stream>>>(tei, cursor, eidx, E);

    // 2) layer 1: g1 = (f16) dinv*(x@W1); h1 = (f16) relu(dinv*(agg+self)+b1)
    {
        dim3 grid((N + 127) / 128, HID / 128);
        k_gemm_mfma<4, true, 8><<<grid, 256, 0, stream>>>(x, W1t, dinv, g1h, N, NFEAT, HID);
        int nblk = (int)(((size_t)N * 64 + 255) / 256);
        k_agg1<<<nblk, 256, 0, stream>>>(rowptr, eidx, g1h, dinv, b1, h1h, N);
    }

    // 3) layer 2: g2 = (f16) dinv*(h1@W2); zs = (f16, [4][N][32]) dinv*(agg+self)+b2
    {
        dim3 grid((N + 63) / 64, OUTF / 128);
        k_gemm_mfma<2, false, 7><<<grid, 256, 0, stream>>>(h1h, W2t, dinv, g2h, N, HID, OUTF);
        int nblk = (int)(((size_t)N * 64 + 255) / 256);
        k_agg2<<<nblk, 256, 0, stream>>>(rowptr, eidx, g2h, dinv, b2, zs, N);
    }

    // 4) decode: sliced pipelined partial dots + final sum
    {
        const int epb = 4 * 32 * DEC_ITER;              // edges per block (1024)
        int nblk = 4 * ((2 * E + epb - 1) / epb);       // 4 slices
        k_decode<<<nblk, 256, 0, stream>>>(pos, neg, zs, psum, E, N);
        k_dsum<<<(2 * E + 255) / 256, 256, 0, stream>>>(psum, out, 2 * E);
    }
}

// Round 4
// 408.308 us; speedup vs baseline: 1.0183x; 1.0119x over previous
//
#include <hip/hip_runtime.h>
#include <hip/hip_fp16.h>

// GCN link-prediction forward. CSR aggregation, row-major fp16 gather tables
// for the aggregates; XCD-sliced L2-resident z for decode (zs[4][N][32], slice
// = blockIdx&3) with dot2-based 0.5-instr/edge/slice gather (32 edges/wave,
// 2 lanes/edge — measured TA-floor form); decode accumulates slices directly
// into out via atomicAdd (no psum round-trip, no dsum pass); fused prep kernel
// (W transposes + deg init + out zero); fp16 MFMA GEMMs; parallel 3-pass
// prefix scan for CSR rowptr.
// Inputs: x[N,256] f32, train_edges[2,E] i32, pos[2,E] i32, neg[2,E] i32,
//         W1[256,256], b1[256], W2[256,128], b2[128]  (all f32)
// Output: logits[2E] f32.

#define NFEAT 256
#define HID   256
#define OUTF  128

typedef _Float16 f16x8 __attribute__((ext_vector_type(8)));
typedef _Float16 f16x2 __attribute__((ext_vector_type(2)));
typedef float    f32x4 __attribute__((ext_vector_type(4)));

// ---------------- W transpose tile body: Wt[m][k] = (half)W[k][m] ------------
__device__ __forceinline__ void wt_body(const float* __restrict__ W,
                                        __half* __restrict__ Wt,
                                        int K, int M, int bxx, int byy) {
    __shared__ float tile[32][33];
    int k0 = bxx * 32, m0 = byy * 32;
    int tx = threadIdx.x & 31, ty = threadIdx.x >> 5;  // ty 0..7
#pragma unroll
    for (int r = 0; r < 4; ++r)
        tile[ty + r * 8][tx] = W[(size_t)(k0 + ty + r * 8) * M + m0 + tx];
    __syncthreads();
#pragma unroll
    for (int r = 0; r < 4; ++r)
        Wt[(size_t)(m0 + ty + r * 8) * K + k0 + tx] = __float2half(tile[tx][ty + r * 8]);
}

// ---------------- fused prep: wt(W1) | wt(W2) | deg=1 | out=0 ----------------
// block ranges: [0,64) W1t 8x8, [64,96) W2t 8x4, [96,96+nbi) deg, rest zero out.
__global__ __launch_bounds__(256) void k_prep(
        const float* __restrict__ W1, __half* __restrict__ W1t,
        const float* __restrict__ W2, __half* __restrict__ W2t,
        float* __restrict__ deg, float* __restrict__ outz, int n, int n2e) {
    int bid = blockIdx.x;
    if (bid < 64) { wt_body(W1, W1t, NFEAT, HID, bid & 7, bid >> 3); return; }
    bid -= 64;
    if (bid < 32) { wt_body(W2, W2t, HID, OUTF, bid & 7, bid >> 3); return; }
    bid -= 32;
    const int nbi = (n + 255) >> 8;
    if (bid < nbi) {
        int i = bid * 256 + threadIdx.x;
        if (i < n) deg[i] = 1.0f;   // self-loop
        return;
    }
    bid -= nbi;
    int i = bid * 256 + threadIdx.x;
    if (i < (n2e >> 2))
        ((float4*)outz)[i] = (float4){0.f, 0.f, 0.f, 0.f};
}

// ---------------- degree count ----------------
__global__ void k_count_deg(const int* __restrict__ ei, float* __restrict__ deg, int E) {
    int e = blockIdx.x * blockDim.x + threadIdx.x;
    if (e < E) atomicAdd(&deg[ei[E + e]], 1.0f);   // dst row
}

// ---------------- parallel scan, pass 1: per-block exclusive scan ----------------
__global__ __launch_bounds__(1024) void k_scan1(
        const float* __restrict__ deg, int* __restrict__ excl,
        int* __restrict__ bsum, int n) {
    __shared__ int swsum[16];
    const int t = threadIdx.x, wave = t >> 6, lane = t & 63;
    const int i = blockIdx.x * 1024 + t;
    int v = (i < n) ? (int)deg[i] - 1 : 0;
    int sc = v;
#pragma unroll
    for (int off = 1; off < 64; off <<= 1) {
        int y = __shfl_up(sc, off);
        if (lane >= off) sc += y;
    }
    if (lane == 63) swsum[wave] = sc;
    __syncthreads();
    if (t < 16) {
        int w = swsum[t];
        int scw = w;
#pragma unroll
        for (int off = 1; off < 16; off <<= 1) {
            int y = __shfl_up(scw, off);
            if (t >= off) scw += y;
        }
        swsum[t] = scw - w;
        if (t == 15) bsum[blockIdx.x] = scw;
    }
    __syncthreads();
    if (i < n) excl[i] = swsum[wave] + (sc - v);
}

// ---------------- pass 2: scan the (<=64) block sums in one wave ----------------
__global__ void k_scan2(int* __restrict__ bsum, int nb) {
    int t = threadIdx.x;          // 64 threads
    int v = (t < nb) ? bsum[t] : 0;
    int sc = v;
#pragma unroll
    for (int off = 1; off < 64; off <<= 1) {
        int y = __shfl_up(sc, off);
        if (t >= off) sc += y;
    }
    if (t < nb) bsum[t] = sc - v;   // exclusive
    if (t == 63) bsum[nb] = sc;     // grand total
}

// ---------------- pass 3: rowptr/cursor/dinv ----------------
__global__ void k_scan3(float* __restrict__ deg_dinv, const int* __restrict__ excl,
                        const int* __restrict__ bsum, int* __restrict__ rowptr,
                        int* __restrict__ cursor, int n, int nb) {
    int i = blockIdx.x * blockDim.x + threadIdx.x;
    if (i < n) {
        int rp = excl[i] + bsum[i >> 10];
        rowptr[i] = rp;
        cursor[i] = rp;
        deg_dinv[i] = rsqrtf(deg_dinv[i]);
    } else if (i == n) {
        rowptr[n] = bsum[nb];
    }
}

// ---------------- fill CSR adjacency (src ids grouped by dst) ----------------
__global__ void k_fill(const int* __restrict__ ei, int* __restrict__ cursor,
                       int* __restrict__ eidx, int E) {
    int e = blockIdx.x * blockDim.x + threadIdx.x;
    if (e < E) {
        int s = ei[e];
        int d = ei[E + e];
        int p = atomicAdd(&cursor[d], 1);
        eidx[p] = s;
    }
}

// ---------------- MFMA GEMM: out = (half)(dinv[r] * A @ Wt^T) ----------------
// Block: 256 threads = 4 waves (2x2). Block tile (2*MT*16) x 128, wave (MT*16) x 64.
// A: [n][K] (f32 if AF32 else f16). Wt: [M][K] f16. K % 32 == 0.
// SWL=8 for M=256 / SWL=7 for M=128 give plain row-major output.
template <int MT, bool AF32, int SWL>
__global__ __launch_bounds__(256) void k_gemm_mfma(
        const void* __restrict__ Aptr, const __half* __restrict__ Wt,
        const float* __restrict__ dinv, __half* __restrict__ outp,
        int n, int K, int M) {
    constexpr int BM = 2 * MT * 16;
    __shared__ __half As[BM][40];      // [row][k], +8 pad: 2-way banks (free)
    __shared__ __half Bs[128][40];     // [col][k]
    __shared__ __half Cs[4][16][72];   // per-wave C repack (16B-aligned rows)

    const int t    = threadIdx.x;
    const int wave = t >> 6;
    const int lane = t & 63;
    const int row0 = blockIdx.x * BM;
    const int col0 = blockIdx.y * 128;
    const int wm = wave >> 1, wn = wave & 1;
    const int lr = lane & 15;          // fragment m/n index
    const int kq = lane >> 4;          // k-quad: k = kq*8 + j

    f32x4 acc[MT][4];
#pragma unroll
    for (int i = 0; i < MT; ++i)
#pragma unroll
        for (int j = 0; j < 4; ++j) acc[i][j] = (f32x4){0.f, 0.f, 0.f, 0.f};

    for (int k0 = 0; k0 < K; k0 += 32) {
        // ---- stage A tile: BM rows x 32 k ----
        if (AF32) {
            const float* A = (const float*)Aptr;
#pragma unroll
            for (int it = 0; it < BM * 8 / 256; ++it) {
                int q = t + it * 256;
                int r = q >> 3, c4 = q & 7;       // c4: which 4-float chunk
                int gr = min(row0 + r, n - 1);
                float4 v = *(const float4*)&A[(size_t)gr * K + k0 + c4 * 4];
                __half2* dst = (__half2*)&As[r][c4 * 4];
                dst[0] = __floats2half2_rn(v.x, v.y);
                dst[1] = __floats2half2_rn(v.z, v.w);
            }
        } else {
            const __half* A = (const __half*)Aptr;
#pragma unroll
            for (int it = 0; it < BM * 4 / 256; ++it) {
                int q = t + it * 256;
                int r = q >> 2, c8 = q & 3;       // c8: which 8-half chunk
                int gr = min(row0 + r, n - 1);
                *(float4*)&As[r][c8 * 8] = *(const float4*)&A[(size_t)gr * K + k0 + c8 * 8];
            }
        }
        // ---- stage B tile: 128 cols x 32 k from Wt ----
#pragma unroll
        for (int it = 0; it < 2; ++it) {
            int q = t + it * 256;
            int r = q >> 2, c8 = q & 3;
            *(float4*)&Bs[r][c8 * 8] = *(const float4*)&Wt[(size_t)(col0 + r) * K + k0 + c8 * 8];
        }
        __syncthreads();

        f16x8 b[4];
#pragma unroll
        for (int j = 0; j < 4; ++j)
            b[j] = *(const f16x8*)&Bs[wn * 64 + j * 16 + lr][kq * 8];
#pragma unroll
        for (int i = 0; i < MT; ++i) {
            f16x8 a = *(const f16x8*)&As[wm * MT * 16 + i * 16 + lr][kq * 8];
#pragma unroll
            for (int j = 0; j < 4; ++j)
                acc[i][j] = __builtin_amdgcn_mfma_f32_16x16x32_f16(a, b[j], acc[i][j], 0, 0, 0);
        }
        __syncthreads();
    }

    // ---- epilogue: scale by dinv, f16 convert, repack via LDS, 16-B stores ----
    constexpr int SW = 1 << SWL;
#pragma unroll
    for (int i = 0; i < MT; ++i) {
        int gr0 = row0 + wm * MT * 16 + i * 16;
        float dv[4];
#pragma unroll
        for (int r = 0; r < 4; ++r)
            dv[r] = dinv[min(gr0 + kq * 4 + r, n - 1)];
        __syncthreads();   // protect Cs reuse across i iterations
#pragma unroll
        for (int j = 0; j < 4; ++j)
#pragma unroll
            for (int r = 0; r < 4; ++r)
                Cs[wave][kq * 4 + r][j * 16 + lr] = __float2half(acc[i][j][r] * dv[r]);
        __syncthreads();
        int r1 = lane >> 3, c1 = (lane & 7) * 8;
#pragma unroll
        for (int h = 0; h < 2; ++h) {
            int grow = gr0 + r1 + h * 8;
            if (grow < n) {
                int col = col0 + wn * 64 + c1;    // multiple of 8
                size_t oidx = ((size_t)(col >> SWL) * n + grow) * SW + (col & (SW - 1));
                *(float4*)&outp[oidx] = *(const float4*)&Cs[wave][r1 + h * 8][c1];
            }
        }
    }
}

// ---------------- layer-1 aggregate: wave per node, 2 edges per load ----------
// g1 row-major [n][256] f16 (512B rows). lane = half(row sel) x 32 chunks x 16B.
__global__ __launch_bounds__(256) void k_agg1(
        const int* __restrict__ rowptr, const int* __restrict__ eidx,
        const __half* __restrict__ g, const float* __restrict__ dinv,
        const float* __restrict__ bias, __half* __restrict__ out, int n) {
    const int node = (int)(((size_t)blockIdx.x * blockDim.x + threadIdx.x) >> 6);
    const int lane = threadIdx.x & 63;
    const int half = lane >> 5;        // which of 2 rows this lane reads
    const int fl   = lane & 31;        // 16B chunk within row (8 halves)
    if (node >= n) return;
    const int j0  = rowptr[node];
    const int end = rowptr[node + 1];
    const int last = end - 1;          // only used when end > j0

    union U { float4 f; __half2 h[4]; };
    float acc[8] = {0.f, 0.f, 0.f, 0.f, 0.f, 0.f, 0.f, 0.f};
    {   // self row: half 0 only (avoid double count)
        if (half == 0) {
            U u; u.f = *(const float4*)&g[(size_t)node * HID + fl * 8];
#pragma unroll
            for (int k = 0; k < 4; ++k) {
                float2 v = __half22float2(u.h[k]);
                acc[k * 2] += v.x; acc[k * 2 + 1] += v.y;
            }
        }
    }
    if (j0 < end) {
        int s0 = eidx[min(j0 + half, last)];
        int s1 = eidx[min(j0 + 2 + half, last)];
        for (int j = j0; j < end; j += 4) {
            int p0 = eidx[min(j + 4 + half, last)];   // prefetch next iter's indices
            int p1 = eidx[min(j + 6 + half, last)];
            U u0, u1;
            u0.f = *(const float4*)&g[(size_t)s0 * HID + fl * 8];
            u1.f = *(const float4*)&g[(size_t)s1 * HID + fl * 8];
            if (j + half < end) {
#pragma unroll
                for (int k = 0; k < 4; ++k) {
                    float2 v = __half22float2(u0.h[k]);
                    acc[k * 2] += v.x; acc[k * 2 + 1] += v.y;
                }
            }
            if (j + 2 + half < end) {
#pragma unroll
                for (int k = 0; k < 4; ++k) {
                    float2 v = __half22float2(u1.h[k]);
                    acc[k * 2] += v.x; acc[k * 2 + 1] += v.y;
                }
            }
            s0 = p0; s1 = p1;
        }
    }
    // reduce across the two halves
#pragma unroll
    for (int k = 0; k < 8; ++k) acc[k] += __shfl_xor(acc[k], 32);
    if (half == 0) {
        const float sc = dinv[node];
        const int f0 = fl * 8;
        U r;
#pragma unroll
        for (int k = 0; k < 4; ++k) {
            float2 bb = *(const float2*)&bias[f0 + k * 2];
            r.h[k] = __floats2half2_rn(fmaxf(sc * acc[k * 2]     + bb.x, 0.f),
                                       fmaxf(sc * acc[k * 2 + 1] + bb.y, 0.f));
        }
        *(float4*)&out[(size_t)node * HID + f0] = r.f;
    }
}

// ---------------- layer-2 aggregate: wave per node, 4 edges per load ----------
// g2 row-major [n][128] f16 (256B rows) -> zs [4][n][32] f16 (sliced for decode).
__global__ __launch_bounds__(256) void k_agg2(
        const int* __restrict__ rowptr, const int* __restrict__ eidx,
        const __half* __restrict__ g, const float* __restrict__ dinv,
        const float* __restrict__ bias, __half* __restrict__ zs, int n) {
    const int node = (int)(((size_t)blockIdx.x * blockDim.x + threadIdx.x) >> 6);
    const int lane = threadIdx.x & 63;
    const int q    = lane >> 4;        // which of 4 rows this lane reads
    const int fl   = lane & 15;        // 16B chunk within row
    if (node >= n) return;
    const int j0  = rowptr[node];
    const int end = rowptr[node + 1];
    const int last = end - 1;

    union U { float4 f; __half2 h[4]; };
    float acc[8] = {0.f, 0.f, 0.f, 0.f, 0.f, 0.f, 0.f, 0.f};
    if (q == 0) {   // self row
        U u; u.f = *(const float4*)&g[(size_t)node * OUTF + fl * 8];
#pragma unroll
        for (int k = 0; k < 4; ++k) {
            float2 v = __half22float2(u.h[k]);
            acc[k * 2] += v.x; acc[k * 2 + 1] += v.y;
        }
    }
    if (j0 < end) {
        int s0 = eidx[min(j0 + q, last)];
        for (int j = j0; j < end; j += 4) {
            int p0 = eidx[min(j + 4 + q, last)];
            U u0; u0.f = *(const float4*)&g[(size_t)s0 * OUTF + fl * 8];
            if (j + q < end) {
#pragma unroll
                for (int k = 0; k < 4; ++k) {
                    float2 v = __half22float2(u0.h[k]);
                    acc[k * 2] += v.x; acc[k * 2 + 1] += v.y;
                }
            }
            s0 = p0;
        }
    }
#pragma unroll
    for (int k = 0; k < 8; ++k) {
        acc[k] += __shfl_xor(acc[k], 16);
        acc[k] += __shfl_xor(acc[k], 32);
    }
    if (q == 0) {
        const float sc = dinv[node];
        const int f0 = fl * 8;              // 0,8,...,120
        U r;
#pragma unroll
        for (int k = 0; k < 4; ++k) {
            float2 bb = *(const float2*)&bias[f0 + k * 2];
            r.h[k] = __floats2half2_rn(sc * acc[k * 2]     + bb.x,
                                       sc * acc[k * 2 + 1] + bb.y);
        }
        // slice-major store: slice = f0>>5, 16B chunk stays within slice
        *(float4*)&zs[((size_t)(f0 >> 5) * n + node) * 32 + (f0 & 31)] = r.f;
    }
}

// ---------------- decode (sliced): atomic partial dots, 32 edges/wave --------
// zs [4][n][32] f16; slice = bx & 3 (XCD-pinned, 3.2MB L2-resident).
// lane = (edge-in-wave)*2 + h; lane loads 32B of BOTH endpoint rows, 16-feat
// dot; slice partials accumulate directly into out via atomicAdd (out is
// zeroed by k_prep; no psum round-trip, no dsum pass).
__global__ __launch_bounds__(256) void k_decode(
        const int* __restrict__ pos, const int* __restrict__ neg,
        const __half* __restrict__ zs, float* __restrict__ outz, int E, int n) {
    const int slice = blockIdx.x & 3;
    const int wv    = threadIdx.x >> 6;
    const int lane  = threadIdx.x & 63;
    const int eo    = lane >> 1;       // edge within wave (0..31)
    const int h     = lane & 1;        // which 32B half of the 64B rows
    int e = ((blockIdx.x >> 2) * 4 + wv) * 32 + eo;
    if (e >= 2 * E) return;
    int a, b;
    if (e < E) { a = pos[e];     b = pos[E + e]; }
    else       { a = neg[e - E]; b = neg[e];     }   // neg row1 at E + (e-E) = e
    const __half* ra = zs + ((size_t)slice * n + a) * 32 + h * 16;
    const __half* rb = zs + ((size_t)slice * n + b) * 32 + h * 16;
    union U { float4 f; f16x2 d[4]; };
    U a0, a1, b0, b1;
    a0.f = *(const float4*)&ra[0];
    a1.f = *(const float4*)&ra[8];
    b0.f = *(const float4*)&rb[0];
    b1.f = *(const float4*)&rb[8];
    float p = 0.f;
#if __has_builtin(__builtin_amdgcn_fdot2)
#pragma unroll
    for (int k = 0; k < 4; ++k) p = __builtin_amdgcn_fdot2(a0.d[k], b0.d[k], p, false);
#pragma unroll
    for (int k = 0; k < 4; ++k) p = __builtin_amdgcn_fdot2(a1.d[k], b1.d[k], p, false);
#else
#pragma unroll
    for (int k = 0; k < 4; ++k) {
        p += (float)a0.d[k][0] * (float)b0.d[k][0] + (float)a0.d[k][1] * (float)b0.d[k][1];
        p += (float)a1.d[k][0] * (float)b1.d[k][0] + (float)a1.d[k][1] * (float)b1.d[k][1];
    }
#endif
    p += __shfl_xor(p, 1);
    if (h == 0)
        atomicAdd(&outz[e], p);
}

extern "C" void kernel_launch(void* const* d_in, const int* in_sizes, int n_in,
                              void* d_out, int out_size, void* d_ws, size_t ws_size,
                              hipStream_t stream) {
    const float* x   = (const float*)d_in[0];
    const int*   tei = (const int*)d_in[1];
    const int*   pos = (const int*)d_in[2];
    const int*   neg = (const int*)d_in[3];
    const float* W1  = (const float*)d_in[4];
    const float* b1  = (const float*)d_in[5];
    const float* W2  = (const float*)d_in[6];
    const float* b2  = (const float*)d_in[7];
    float* out = (float*)d_out;

    const int N = in_sizes[0] / NFEAT;    // 50000
    const int E = in_sizes[1] / 2;        // 800000
    const int NB = (N + 1023) / 1024;     // scan blocks (49)

    char* ws = (char*)d_ws;
    size_t off = 0;
    __half* g1h = (__half*)(ws + off);                 // [N][256] f16 (25.6MB)
    __half* g2h = (__half*)(ws + off);                 // [N][128] f16 (g1 dead)
    __half* zs  = (__half*)(ws + off + (size_t)N * OUTF * 2);   // [4][N][32] f16
    off += (size_t)N * HID * 2;
    __half* h1h  = (__half*)(ws + off);                // [N][256] f16 (25.6MB)
    off += (size_t)N * HID * 2;
    float*  dinv = (float*)(ws + off);  off += (size_t)N * 4;
    int* rowptr = (int*)(ws + off);     off += (size_t)(N + 1) * 4;
    int* cursor = (int*)(ws + off);     off += (size_t)N * 4;
    int* eidx   = (int*)(ws + off);     off += (size_t)E * 4;
    __half* W1t = (__half*)(ws + off);  off += (size_t)NFEAT * HID * 2;
    __half* W2t = (__half*)(ws + off);  off += (size_t)HID * OUTF * 2;
    int* excl   = (int*)(ws + off);     off += (size_t)N * 4;
    int* bsum   = (int*)(ws + off);     off += (size_t)(NB + 1) * 4;

    // 0) fused prep: W transposes, deg=1, out=0 (out must be zero before decode)
    {
        int nbi = (N + 255) / 256;
        int nbz = (2 * E / 4 + 255) / 256;
        k_prep<<<64 + 32 + nbi + nbz, 256, 0, stream>>>(W1, W1t, W2, W2t, dinv, out, N, 2 * E);
    }

    // 1) degree -> parallel scan -> CSR fill (shared by both layers)
    k_count_deg<<<(E + 255) / 256, 256, 0, stream>>>(tei, dinv, E);
    k_scan1<<<NB, 1024, 0, stream>>>(dinv, excl, bsum, N);
    k_scan2<<<1, 64, 0, stream>>>(bsum, NB);
    k_scan3<<<(N + 256) / 256, 256, 0, stream>>>(dinv, excl, bsum, rowptr, cursor, N, NB);
    k_fill<<<(E + 255) / 256, 256, 0, stream>>>(tei, cursor, eidx, E);

    // 2) layer 1: g1 = (f16) dinv*(x@W1); h1 = (f16) relu(dinv*(agg+self)+b1)
    {
        dim3 grid((N + 127) / 128, HID / 128);
        k_gemm_mfma<4, true, 8><<<grid, 256, 0, stream>>>(x, W1t, dinv, g1h, N, NFEAT, HID);
        int nblk = (int)(((size_t)N * 64 + 255) / 256);
        k_agg1<<<nblk, 256, 0, stream>>>(rowptr, eidx, g1h, dinv, b1, h1h, N);
    }

    // 3) layer 2: g2 = (f16) dinv*(h1@W2); zs = (f16, [4][N][32]) dinv*(agg+self)+b2
    {
        dim3 grid((N + 63) / 64, OUTF / 128);
        k_gemm_mfma<2, false, 7><<<grid, 256, 0, stream>>>(h1h, W2t, dinv, g2h, N, HID, OUTF);
        int nblk = (int)(((size_t)N * 64 + 255) / 256);
        k_agg2<<<nblk, 256, 0, stream>>>(rowptr, eidx, g2h, dinv, b2, zs, N);
    }

    // 4) decode: sliced partial dots, atomic accumulation into out
    {
        int nblk = 4 * ((2 * E + 127) / 128);   // 4 waves x 32 edges per block
        k_decode<<<nblk, 256, 0, stream>>>(pos, neg, zs, out, E, N);
    }
}

// Round 5
// 399.092 us; speedup vs baseline: 1.0418x; 1.0231x over previous
//
#include <hip/hip_runtime.h>
#include <hip/hip_fp16.h>

// GCN link-prediction forward. CSR aggregation, row-major fp16 gather tables
// for the aggregates; XCD-sliced L2-resident z for decode (zs[4][N][32], slice
// = blockIdx&3) with dot2-based 0.5-instr/edge/slice gather (32 edges/wave,
// 2 lanes/edge — measured TA-floor form, R0-identical); psum + nontemporal
// stores + dsum (measured faster than atomics); fused prep kernel (W
// transposes + deg init); scan2 folded into scan3 (each block re-scans the
// <=64 raw block sums); fp16 MFMA GEMMs.
// Inputs: x[N,256] f32, train_edges[2,E] i32, pos[2,E] i32, neg[2,E] i32,
//         W1[256,256], b1[256], W2[256,128], b2[128]  (all f32)
// Output: logits[2E] f32.

#define NFEAT 256
#define HID   256
#define OUTF  128

typedef _Float16 f16x8 __attribute__((ext_vector_type(8)));
typedef _Float16 f16x2 __attribute__((ext_vector_type(2)));
typedef float    f32x4 __attribute__((ext_vector_type(4)));

// ---------------- W transpose tile body: Wt[m][k] = (half)W[k][m] ------------
__device__ __forceinline__ void wt_body(const float* __restrict__ W,
                                        __half* __restrict__ Wt,
                                        int K, int M, int bxx, int byy) {
    __shared__ float tile[32][33];
    int k0 = bxx * 32, m0 = byy * 32;
    int tx = threadIdx.x & 31, ty = threadIdx.x >> 5;  // ty 0..7
#pragma unroll
    for (int r = 0; r < 4; ++r)
        tile[ty + r * 8][tx] = W[(size_t)(k0 + ty + r * 8) * M + m0 + tx];
    __syncthreads();
#pragma unroll
    for (int r = 0; r < 4; ++r)
        Wt[(size_t)(m0 + ty + r * 8) * K + k0 + tx] = __float2half(tile[tx][ty + r * 8]);
}

// ---------------- fused prep: wt(W1) | wt(W2) | deg=1 ----------------
// block ranges: [0,64) W1t 8x8, [64,96) W2t 8x4, rest deg init.
__global__ __launch_bounds__(256) void k_prep(
        const float* __restrict__ W1, __half* __restrict__ W1t,
        const float* __restrict__ W2, __half* __restrict__ W2t,
        float* __restrict__ deg, int n) {
    int bid = blockIdx.x;
    if (bid < 64) { wt_body(W1, W1t, NFEAT, HID, bid & 7, bid >> 3); return; }
    bid -= 64;
    if (bid < 32) { wt_body(W2, W2t, HID, OUTF, bid & 7, bid >> 3); return; }
    bid -= 32;
    int i = bid * 256 + threadIdx.x;
    if (i < n) deg[i] = 1.0f;   // self-loop
}

// ---------------- degree count ----------------
__global__ void k_count_deg(const int* __restrict__ ei, float* __restrict__ deg, int E) {
    int e = blockIdx.x * blockDim.x + threadIdx.x;
    if (e < E) atomicAdd(&deg[ei[E + e]], 1.0f);   // dst row
}

// ---------------- parallel scan, pass 1: per-block exclusive scan ----------------
// bsum[b] gets the RAW per-block total (scan of totals happens in k_scan3).
__global__ __launch_bounds__(1024) void k_scan1(
        const float* __restrict__ deg, int* __restrict__ excl,
        int* __restrict__ bsum, int n) {
    __shared__ int swsum[16];
    const int t = threadIdx.x, wave = t >> 6, lane = t & 63;
    const int i = blockIdx.x * 1024 + t;
    int v = (i < n) ? (int)deg[i] - 1 : 0;
    int sc = v;
#pragma unroll
    for (int off = 1; off < 64; off <<= 1) {
        int y = __shfl_up(sc, off);
        if (lane >= off) sc += y;
    }
    if (lane == 63) swsum[wave] = sc;
    __syncthreads();
    if (t < 16) {
        int w = swsum[t];
        int scw = w;
#pragma unroll
        for (int off = 1; off < 16; off <<= 1) {
            int y = __shfl_up(scw, off);
            if (t >= off) scw += y;
        }
        swsum[t] = scw - w;
        if (t == 15) bsum[blockIdx.x] = scw;
    }
    __syncthreads();
    if (i < n) excl[i] = swsum[wave] + (sc - v);
}

// ---------------- pass 2 (fused): rowptr/cursor/dinv; wave 0 scans bsum ------
// Each block re-scans the <=64 raw block totals into an exclusive prefix (LDS),
// then applies it. nb <= 64 required (N <= 65536).
__global__ __launch_bounds__(256) void k_scan3(
        float* __restrict__ deg_dinv, const int* __restrict__ excl,
        const int* __restrict__ bsum, int* __restrict__ rowptr,
        int* __restrict__ cursor, int n, int nb) {
    __shared__ int pbs[65];
    const int t = threadIdx.x;
    if (t < 64) {
        int v = (t < nb) ? bsum[t] : 0;
        int sc = v;
#pragma unroll
        for (int off = 1; off < 64; off <<= 1) {
            int y = __shfl_up(sc, off);
            if (t >= off) sc += y;
        }
        pbs[t] = sc - v;            // exclusive prefix of block totals
        if (t == 63) pbs[64] = sc;  // grand total
    }
    __syncthreads();
    int i = blockIdx.x * 256 + t;
    if (i < n) {
        int rp = excl[i] + pbs[i >> 10];
        rowptr[i] = rp;
        cursor[i] = rp;
        deg_dinv[i] = rsqrtf(deg_dinv[i]);
    } else if (i == n) {
        rowptr[n] = pbs[64];
    }
}

// ---------------- fill CSR adjacency (src ids grouped by dst) ----------------
__global__ void k_fill(const int* __restrict__ ei, int* __restrict__ cursor,
                       int* __restrict__ eidx, int E) {
    int e = blockIdx.x * blockDim.x + threadIdx.x;
    if (e < E) {
        int s = ei[e];
        int d = ei[E + e];
        int p = atomicAdd(&cursor[d], 1);
        eidx[p] = s;
    }
}

// ---------------- MFMA GEMM: out = (half)(dinv[r] * A @ Wt^T) ----------------
// Block: 256 threads = 4 waves (2x2). Block tile (2*MT*16) x 128, wave (MT*16) x 64.
// A: [n][K] (f32 if AF32 else f16). Wt: [M][K] f16. K % 32 == 0.
// SWL=8 for M=256 / SWL=7 for M=128 give plain row-major output.
template <int MT, bool AF32, int SWL>
__global__ __launch_bounds__(256) void k_gemm_mfma(
        const void* __restrict__ Aptr, const __half* __restrict__ Wt,
        const float* __restrict__ dinv, __half* __restrict__ outp,
        int n, int K, int M) {
    constexpr int BM = 2 * MT * 16;
    __shared__ __half As[BM][40];      // [row][k], +8 pad: 2-way banks (free)
    __shared__ __half Bs[128][40];     // [col][k]
    __shared__ __half Cs[4][16][72];   // per-wave C repack (16B-aligned rows)

    const int t    = threadIdx.x;
    const int wave = t >> 6;
    const int lane = t & 63;
    const int row0 = blockIdx.x * BM;
    const int col0 = blockIdx.y * 128;
    const int wm = wave >> 1, wn = wave & 1;
    const int lr = lane & 15;          // fragment m/n index
    const int kq = lane >> 4;          // k-quad: k = kq*8 + j

    f32x4 acc[MT][4];
#pragma unroll
    for (int i = 0; i < MT; ++i)
#pragma unroll
        for (int j = 0; j < 4; ++j) acc[i][j] = (f32x4){0.f, 0.f, 0.f, 0.f};

    for (int k0 = 0; k0 < K; k0 += 32) {
        // ---- stage A tile: BM rows x 32 k ----
        if (AF32) {
            const float* A = (const float*)Aptr;
#pragma unroll
            for (int it = 0; it < BM * 8 / 256; ++it) {
                int q = t + it * 256;
                int r = q >> 3, c4 = q & 7;       // c4: which 4-float chunk
                int gr = min(row0 + r, n - 1);
                float4 v = *(const float4*)&A[(size_t)gr * K + k0 + c4 * 4];
                __half2* dst = (__half2*)&As[r][c4 * 4];
                dst[0] = __floats2half2_rn(v.x, v.y);
                dst[1] = __floats2half2_rn(v.z, v.w);
            }
        } else {
            const __half* A = (const __half*)Aptr;
#pragma unroll
            for (int it = 0; it < BM * 4 / 256; ++it) {
                int q = t + it * 256;
                int r = q >> 2, c8 = q & 3;       // c8: which 8-half chunk
                int gr = min(row0 + r, n - 1);
                *(float4*)&As[r][c8 * 8] = *(const float4*)&A[(size_t)gr * K + k0 + c8 * 8];
            }
        }
        // ---- stage B tile: 128 cols x 32 k from Wt ----
#pragma unroll
        for (int it = 0; it < 2; ++it) {
            int q = t + it * 256;
            int r = q >> 2, c8 = q & 3;
            *(float4*)&Bs[r][c8 * 8] = *(const float4*)&Wt[(size_t)(col0 + r) * K + k0 + c8 * 8];
        }
        __syncthreads();

        f16x8 b[4];
#pragma unroll
        for (int j = 0; j < 4; ++j)
            b[j] = *(const f16x8*)&Bs[wn * 64 + j * 16 + lr][kq * 8];
#pragma unroll
        for (int i = 0; i < MT; ++i) {
            f16x8 a = *(const f16x8*)&As[wm * MT * 16 + i * 16 + lr][kq * 8];
#pragma unroll
            for (int j = 0; j < 4; ++j)
                acc[i][j] = __builtin_amdgcn_mfma_f32_16x16x32_f16(a, b[j], acc[i][j], 0, 0, 0);
        }
        __syncthreads();
    }

    // ---- epilogue: scale by dinv, f16 convert, repack via LDS, 16-B stores ----
    constexpr int SW = 1 << SWL;
#pragma unroll
    for (int i = 0; i < MT; ++i) {
        int gr0 = row0 + wm * MT * 16 + i * 16;
        float dv[4];
#pragma unroll
        for (int r = 0; r < 4; ++r)
            dv[r] = dinv[min(gr0 + kq * 4 + r, n - 1)];
        __syncthreads();   // protect Cs reuse across i iterations
#pragma unroll
        for (int j = 0; j < 4; ++j)
#pragma unroll
            for (int r = 0; r < 4; ++r)
                Cs[wave][kq * 4 + r][j * 16 + lr] = __float2half(acc[i][j][r] * dv[r]);
        __syncthreads();
        int r1 = lane >> 3, c1 = (lane & 7) * 8;
#pragma unroll
        for (int h = 0; h < 2; ++h) {
            int grow = gr0 + r1 + h * 8;
            if (grow < n) {
                int col = col0 + wn * 64 + c1;    // multiple of 8
                size_t oidx = ((size_t)(col >> SWL) * n + grow) * SW + (col & (SW - 1));
                *(float4*)&outp[oidx] = *(const float4*)&Cs[wave][r1 + h * 8][c1];
            }
        }
    }
}

// ---------------- layer-1 aggregate: wave per node, 2 edges per load ----------
// g1 row-major [n][256] f16 (512B rows). lane = half(row sel) x 32 chunks x 16B.
__global__ __launch_bounds__(256) void k_agg1(
        const int* __restrict__ rowptr, const int* __restrict__ eidx,
        const __half* __restrict__ g, const float* __restrict__ dinv,
        const float* __restrict__ bias, __half* __restrict__ out, int n) {
    const int node = (int)(((size_t)blockIdx.x * blockDim.x + threadIdx.x) >> 6);
    const int lane = threadIdx.x & 63;
    const int half = lane >> 5;        // which of 2 rows this lane reads
    const int fl   = lane & 31;        // 16B chunk within row (8 halves)
    if (node >= n) return;
    const int j0  = rowptr[node];
    const int end = rowptr[node + 1];
    const int last = end - 1;          // only used when end > j0

    union U { float4 f; __half2 h[4]; };
    float acc[8] = {0.f, 0.f, 0.f, 0.f, 0.f, 0.f, 0.f, 0.f};
    {   // self row: half 0 only (avoid double count)
        if (half == 0) {
            U u; u.f = *(const float4*)&g[(size_t)node * HID + fl * 8];
#pragma unroll
            for (int k = 0; k < 4; ++k) {
                float2 v = __half22float2(u.h[k]);
                acc[k * 2] += v.x; acc[k * 2 + 1] += v.y;
            }
        }
    }
    if (j0 < end) {
        int s0 = eidx[min(j0 + half, last)];
        int s1 = eidx[min(j0 + 2 + half, last)];
        for (int j = j0; j < end; j += 4) {
            int p0 = eidx[min(j + 4 + half, last)];   // prefetch next iter's indices
            int p1 = eidx[min(j + 6 + half, last)];
            U u0, u1;
            u0.f = *(const float4*)&g[(size_t)s0 * HID + fl * 8];
            u1.f = *(const float4*)&g[(size_t)s1 * HID + fl * 8];
            if (j + half < end) {
#pragma unroll
                for (int k = 0; k < 4; ++k) {
                    float2 v = __half22float2(u0.h[k]);
                    acc[k * 2] += v.x; acc[k * 2 + 1] += v.y;
                }
            }
            if (j + 2 + half < end) {
#pragma unroll
                for (int k = 0; k < 4; ++k) {
                    float2 v = __half22float2(u1.h[k]);
                    acc[k * 2] += v.x; acc[k * 2 + 1] += v.y;
                }
            }
            s0 = p0; s1 = p1;
        }
    }
    // reduce across the two halves
#pragma unroll
    for (int k = 0; k < 8; ++k) acc[k] += __shfl_xor(acc[k], 32);
    if (half == 0) {
        const float sc = dinv[node];
        const int f0 = fl * 8;
        U r;
#pragma unroll
        for (int k = 0; k < 4; ++k) {
            float2 bb = *(const float2*)&bias[f0 + k * 2];
            r.h[k] = __floats2half2_rn(fmaxf(sc * acc[k * 2]     + bb.x, 0.f),
                                       fmaxf(sc * acc[k * 2 + 1] + bb.y, 0.f));
        }
        *(float4*)&out[(size_t)node * HID + f0] = r.f;
    }
}

// ---------------- layer-2 aggregate: wave per node, 4 edges per load ----------
// g2 row-major [n][128] f16 (256B rows) -> zs [4][n][32] f16 (sliced for decode).
__global__ __launch_bounds__(256) void k_agg2(
        const int* __restrict__ rowptr, const int* __restrict__ eidx,
        const __half* __restrict__ g, const float* __restrict__ dinv,
        const float* __restrict__ bias, __half* __restrict__ zs, int n) {
    const int node = (int)(((size_t)blockIdx.x * blockDim.x + threadIdx.x) >> 6);
    const int lane = threadIdx.x & 63;
    const int q    = lane >> 4;        // which of 4 rows this lane reads
    const int fl   = lane & 15;        // 16B chunk within row
    if (node >= n) return;
    const int j0  = rowptr[node];
    const int end = rowptr[node + 1];
    const int last = end - 1;

    union U { float4 f; __half2 h[4]; };
    float acc[8] = {0.f, 0.f, 0.f, 0.f, 0.f, 0.f, 0.f, 0.f};
    if (q == 0) {   // self row
        U u; u.f = *(const float4*)&g[(size_t)node * OUTF + fl * 8];
#pragma unroll
        for (int k = 0; k < 4; ++k) {
            float2 v = __half22float2(u.h[k]);
            acc[k * 2] += v.x; acc[k * 2 + 1] += v.y;
        }
    }
    if (j0 < end) {
        int s0 = eidx[min(j0 + q, last)];
        for (int j = j0; j < end; j += 4) {
            int p0 = eidx[min(j + 4 + q, last)];
            U u0; u0.f = *(const float4*)&g[(size_t)s0 * OUTF + fl * 8];
            if (j + q < end) {
#pragma unroll
                for (int k = 0; k < 4; ++k) {
                    float2 v = __half22float2(u0.h[k]);
                    acc[k * 2] += v.x; acc[k * 2 + 1] += v.y;
                }
            }
            s0 = p0;
        }
    }
#pragma unroll
    for (int k = 0; k < 8; ++k) {
        acc[k] += __shfl_xor(acc[k], 16);
        acc[k] += __shfl_xor(acc[k], 32);
    }
    if (q == 0) {
        const float sc = dinv[node];
        const int f0 = fl * 8;              // 0,8,...,120
        U r;
#pragma unroll
        for (int k = 0; k < 4; ++k) {
            float2 bb = *(const float2*)&bias[f0 + k * 2];
            r.h[k] = __floats2half2_rn(sc * acc[k * 2]     + bb.x,
                                       sc * acc[k * 2 + 1] + bb.y);
        }
        // slice-major store: slice = f0>>5, 16B chunk stays within slice
        *(float4*)&zs[((size_t)(f0 >> 5) * n + node) * 32 + (f0 & 31)] = r.f;
    }
}

// ---------------- decode (sliced): psum[slice][e], 32 edges/wave ----------------
// zs [4][n][32] f16; slice = bx & 3 (XCD-pinned, 3.2MB L2-resident).
// lane = (edge-in-wave)*2 + h; lane loads 32B of BOTH endpoint rows, 16-feat dot.
__global__ __launch_bounds__(256) void k_decode(
        const int* __restrict__ pos, const int* __restrict__ neg,
        const __half* __restrict__ zs, float* __restrict__ psum, int E, int n) {
    const int slice = blockIdx.x & 3;
    const int wv    = threadIdx.x >> 6;
    const int lane  = threadIdx.x & 63;
    const int eo    = lane >> 1;       // edge within wave (0..31)
    const int h     = lane & 1;        // which 32B half of the 64B rows
    int e = ((blockIdx.x >> 2) * 4 + wv) * 32 + eo;
    if (e >= 2 * E) return;
    int a, b;
    if (e < E) { a = pos[e];     b = pos[E + e]; }
    else       { a = neg[e - E]; b = neg[e];     }   // neg row1 at E + (e-E) = e
    const __half* ra = zs + ((size_t)slice * n + a) * 32 + h * 16;
    const __half* rb = zs + ((size_t)slice * n + b) * 32 + h * 16;
    union U { float4 f; f16x2 d[4]; };
    U a0, a1, b0, b1;
    a0.f = *(const float4*)&ra[0];
    a1.f = *(const float4*)&ra[8];
    b0.f = *(const float4*)&rb[0];
    b1.f = *(const float4*)&rb[8];
    float p = 0.f;
#if __has_builtin(__builtin_amdgcn_fdot2)
#pragma unroll
    for (int k = 0; k < 4; ++k) p = __builtin_amdgcn_fdot2(a0.d[k], b0.d[k], p, false);
#pragma unroll
    for (int k = 0; k < 4; ++k) p = __builtin_amdgcn_fdot2(a1.d[k], b1.d[k], p, false);
#else
#pragma unroll
    for (int k = 0; k < 4; ++k) {
        p += (float)a0.d[k][0] * (float)b0.d[k][0] + (float)a0.d[k][1] * (float)b0.d[k][1];
        p += (float)a1.d[k][0] * (float)b1.d[k][0] + (float)a1.d[k][1] * (float)b1.d[k][1];
    }
#endif
    p += __shfl_xor(p, 1);
    if (h == 0)
        __builtin_nontemporal_store(p, &psum[(size_t)slice * 2 * E + e]);
}

// ---------------- final sum over 4 slices ----------------
__global__ void k_dsum(const float* __restrict__ psum, float* __restrict__ out, int n2e) {
    int e = blockIdx.x * blockDim.x + threadIdx.x;
    if (e < n2e) {
        float p0 = __builtin_nontemporal_load(&psum[e]);
        float p1 = __builtin_nontemporal_load(&psum[(size_t)n2e + e]);
        float p2 = __builtin_nontemporal_load(&psum[2 * (size_t)n2e + e]);
        float p3 = __builtin_nontemporal_load(&psum[3 * (size_t)n2e + e]);
        out[e] = (p0 + p1) + (p2 + p3);
    }
}

extern "C" void kernel_launch(void* const* d_in, const int* in_sizes, int n_in,
                              void* d_out, int out_size, void* d_ws, size_t ws_size,
                              hipStream_t stream) {
    const float* x   = (const float*)d_in[0];
    const int*   tei = (const int*)d_in[1];
    const int*   pos = (const int*)d_in[2];
    const int*   neg = (const int*)d_in[3];
    const float* W1  = (const float*)d_in[4];
    const float* b1  = (const float*)d_in[5];
    const float* W2  = (const float*)d_in[6];
    const float* b2  = (const float*)d_in[7];
    float* out = (float*)d_out;

    const int N = in_sizes[0] / NFEAT;    // 50000
    const int E = in_sizes[1] / 2;        // 800000
    const int NB = (N + 1023) / 1024;     // scan blocks (49)

    char* ws = (char*)d_ws;
    size_t off = 0;
    __half* g1h = (__half*)(ws + off);                 // [N][256] f16 (25.6MB)
    __half* g2h = (__half*)(ws + off);                 // [N][128] f16 (g1 dead)
    __half* zs  = (__half*)(ws + off + (size_t)N * OUTF * 2);   // [4][N][32] f16
    off += (size_t)N * HID * 2;
    __half* h1h  = (__half*)(ws + off);                // [N][256] f16 (25.6MB)
    float*  psum = (float*)(ws + off);                 // [4][2E] f32 (h1 dead after gemm2)
    off += (size_t)N * HID * 2;
    float*  dinv = (float*)(ws + off);  off += (size_t)N * 4;
    int* rowptr = (int*)(ws + off);     off += (size_t)(N + 1) * 4;
    int* cursor = (int*)(ws + off);     off += (size_t)N * 4;
    int* eidx   = (int*)(ws + off);     off += (size_t)E * 4;
    __half* W1t = (__half*)(ws + off);  off += (size_t)NFEAT * HID * 2;
    __half* W2t = (__half*)(ws + off);  off += (size_t)HID * OUTF * 2;
    int* excl   = (int*)(ws + off);     off += (size_t)N * 4;
    int* bsum   = (int*)(ws + off);     off += (size_t)(NB + 1) * 4;

    // 0) fused prep: W transposes + deg init
    {
        int nbi = (N + 255) / 256;
        k_prep<<<64 + 32 + nbi, 256, 0, stream>>>(W1, W1t, W2, W2t, dinv, N);
    }

    // 1) degree -> parallel scan (scan2 fused into scan3) -> CSR fill
    k_count_deg<<<(E + 255) / 256, 256, 0, stream>>>(tei, dinv, E);
    k_scan1<<<NB, 1024, 0, stream>>>(dinv, excl, bsum, N);
    k_scan3<<<(N + 256) / 256, 256, 0, stream>>>(dinv, excl, bsum, rowptr, cursor, N, NB);
    k_fill<<<(E + 255) / 256, 256, 0, stream>>>(tei, cursor, eidx, E);

    // 2) layer 1: g1 = (f16) dinv*(x@W1); h1 = (f16) relu(dinv*(agg+self)+b1)
    {
        dim3 grid((N + 127) / 128, HID / 128);
        k_gemm_mfma<4, true, 8><<<grid, 256, 0, stream>>>(x, W1t, dinv, g1h, N, NFEAT, HID);
        int nblk = (int)(((size_t)N * 64 + 255) / 256);
        k_agg1<<<nblk, 256, 0, stream>>>(rowptr, eidx, g1h, dinv, b1, h1h, N);
    }

    // 3) layer 2: g2 = (f16) dinv*(h1@W2); zs = (f16, [4][N][32]) dinv*(agg+self)+b2
    {
        dim3 grid((N + 63) / 64, OUTF / 128);
        k_gemm_mfma<2, false, 7><<<grid, 256, 0, stream>>>(h1h, W2t, dinv, g2h, N, HID, OUTF);
        int nblk = (int)(((size_t)N * 64 + 255) / 256);
        k_agg2<<<nblk, 256, 0, stream>>>(rowptr, eidx, g2h, dinv, b2, zs, N);
    }

    // 4) decode: sliced partial dots + final sum
    {
        int nblk = 4 * ((2 * E + 127) / 128);   // 4 waves x 32 edges per block
        k_decode<<<nblk, 256, 0, stream>>>(pos, neg, zs, psum, E, N);
        k_dsum<<<(2 * E + 255) / 256, 256, 0, stream>>>(psum, out, 2 * E);
    }
}